// Round 9
// baseline (222.817 us; speedup 1.0000x reference)
//
#include <hip/hip_runtime.h>

// B=4, C=256, H=W=64 (N=4096). QKV 1x1conv -> spatial attention (softmax over
// j only => independent per-64-key-chunk softmax) -> channel LayerNorm.
// f16 MFMA 32x32x16, fp32 accumulation.
//
// R15: two independent changes.
// attn: 2-barrier software pipeline. V fragments held in REGISTERS (R10's
//   proven pattern; R11 measured the LDS alternative at only +2%) and PV of
//   chunk i-1 executes inside iteration i right after chunk i's softmax
//   reduce -> MFMA||VALU dual-pipe overlap (T15 mechanism). Pl double-
//   buffered; Vs deleted -> LDS 80.9->53.2 KB, 2 LBARs/chunk (was 3),
//   LDS traffic/chunk -60%. QK/softmax/merge/Pwrite code identical to R14.
// gemm: weights pre-converted to f16 by a tiny 12-block wconv kernel (proven
//   prep code); gemm stages Wh from f16 with REGISTER PREFETCH across rounds
//   (attn's kreg pattern, never applied here before); all barriers -> LBAR.
//   Xs fp32-direct staging, MFMA loop, epilogue, stores unchanged.
// merge_ln unchanged (proven).

#define CDIM 256
#define NPOS 4096
#define BATCH 4
#define EPSV 1e-5f

typedef _Float16 f16;
typedef __attribute__((ext_vector_type(4))) _Float16 f16x4;
typedef __attribute__((ext_vector_type(8))) _Float16 f16x8;
typedef __attribute__((ext_vector_type(4))) float f32x4;
typedef __attribute__((ext_vector_type(16))) float f32x16;

#define WST       264   // f16; 528B = 33*16 -> b128-aligned rows
#define QK_STRIDE 264   // f16 K-tile rows
#define P_STRIDE  72    // f16 P rows; 144B = 9*16
#define DQ_STRIDE 72
#define F_STRIDE  68    // merge kernel LDS stride (f32)

// LDS-only barrier: prior LDS ops complete, global loads stay in flight.
#define LBAR() asm volatile("s_waitcnt lgkmcnt(0)\n\ts_barrier" ::: "memory")

// MFMA 32x32x16 f16:
//   A: lane l holds A[m=l&31][k=(l>>5)*8+j]
//   B: lane l holds B[k=(l>>5)*8+j][n=l&31]   (same register layout as A)
//   C/D: lane l, reg r -> row m=(r&3)+8*(r>>2)+4*(l>>5), col n=l&31

static __device__ __forceinline__ f16x8 cvt8(const float* __restrict__ p) {
    float4 w0 = *(const float4*)p;
    float4 w1 = *(const float4*)(p + 4);
    f16x8 r;
    r[0] = (f16)w0.x; r[1] = (f16)w0.y; r[2] = (f16)w0.z; r[3] = (f16)w0.w;
    r[4] = (f16)w1.x; r[5] = (f16)w1.y; r[6] = (f16)w1.z; r[7] = (f16)w1.w;
    return r;
}

// ---------------------------------------------------------------------------
// wconv: 12 blocks convert fp32 weights -> f16 [o][c] (proven prep code).
// ---------------------------------------------------------------------------
__global__ __launch_bounds__(256, 4) void wconv_kernel(
    const float* __restrict__ qw, const float* __restrict__ kw,
    const float* __restrict__ vw, f16* __restrict__ W16)
{
    const int id = blockIdx.x;           // 0..11
    const int t  = threadIdx.x;
    const int pr = id >> 2, h = id & 3;
    const float* W = (pr == 0 ? qw : pr == 1 ? kw : vw) + (size_t)h * 64 * CDIM;
    f16* D = W16 + (size_t)pr * CDIM * CDIM + (size_t)h * 64 * CDIM;
    #pragma unroll
    for (int i = 0; i < 8; ++i) {
        int g = t + i * 256;
        int row = g >> 5, col = (g & 31) * 8;
        *(f16x8*)(D + (size_t)row * CDIM + col) = cvt8(W + (size_t)row * CDIM + col);
    }
}

// ---------------------------------------------------------------------------
// gemm: 768 blocks = (pr, b, ptile). Xs staged from fp32 x (transpose in
// LDS staging, as R14); Wh staged from f16 W16 with cross-round register
// prefetch; LBAR barriers. MFMA loop + epilogue + stores unchanged (proven).
// ---------------------------------------------------------------------------
__global__ __launch_bounds__(256, 2) void gemm_kernel(
    const float* __restrict__ x1, const float* __restrict__ x2,
    const f16* __restrict__ W16,
    const float* __restrict__ qb, const float* __restrict__ kb,
    const float* __restrict__ vb,
    f16* __restrict__ Qg, f16* __restrict__ Kg, f16* __restrict__ Vg)
{
    __shared__ f16 Xs[64 * WST];
    __shared__ f16 Wh[64 * WST];
    __shared__ f16 Ds[64 * DQ_STRIDE];
    __shared__ float biasS[256];

    const int id = blockIdx.x;
    const int pr  = id >> 8;
    const int rem = id & 255;
    const int b   = rem >> 6;
    const int p0  = (rem & 63) << 6;
    const float* xsrc = ((pr == 0) ? x1 : x2) + (size_t)b * CDIM * NPOS + p0;
    const f16* Wp = W16 + (size_t)pr * CDIM * CDIM;
    const float* bias = (pr == 0) ? qb : (pr == 1) ? kb : vb;

    const int t = threadIdx.x, w = t >> 6, l = t & 63, lm = l & 31, lh = l >> 5;
    const int pt = w & 1, ot = w >> 1;

    // W register prefetch (f16, 32 VGPR)
    f16x8 wreg[8];
    auto issue_w = [&](int q) {
        #pragma unroll
        for (int i = 0; i < 8; ++i) {
            int g = t + i * 256;
            int row = g >> 5, col = (g & 31) * 8;
            wreg[i] = *(const f16x8*)(Wp + (size_t)(q * 64 + row) * CDIM + col);
        }
    };
    issue_w(0);

    biasS[t] = bias[t];
    // Xs[p][c] <- x[b][c][p0+p], fp32->f16 (transpose via staging, as R14)
    #pragma unroll
    for (int g = 0; g < 8; ++g) {
        f16x8 h;
        #pragma unroll
        for (int j = 0; j < 8; ++j)
            h[j] = (f16)xsrc[(size_t)(w * 64 + g * 8 + j) * NPOS + l];
        *(f16x8*)&Xs[l * WST + w * 64 + g * 8] = h;
    }

    for (int q = 0; q < 4; ++q) {
        // commit prefetched W, then issue next round's W loads
        #pragma unroll
        for (int i = 0; i < 8; ++i) {
            int g = t + i * 256;
            int row = g >> 5, col = (g & 31) * 8;
            *(f16x8*)&Wh[row * WST + col] = wreg[i];
        }
        if (q < 3) issue_w(q + 1);
        LBAR();

        f32x16 accA = {}, accB = {};
        #pragma unroll
        for (int ks = 0; ks < 16; ks += 2) {
            f16x8 x0 = *(const f16x8*)&Xs[(pt * 32 + lm) * WST + ks * 16 + lh * 8];
            f16x8 w0 = *(const f16x8*)&Wh[(ot * 32 + lm) * WST + ks * 16 + lh * 8];
            f16x8 x1v = *(const f16x8*)&Xs[(pt * 32 + lm) * WST + (ks + 1) * 16 + lh * 8];
            f16x8 w1 = *(const f16x8*)&Wh[(ot * 32 + lm) * WST + (ks + 1) * 16 + lh * 8];
            if (pr < 2) {
                accA = __builtin_amdgcn_mfma_f32_32x32x16_f16(x0, w0, accA, 0, 0, 0);
                accB = __builtin_amdgcn_mfma_f32_32x32x16_f16(x1v, w1, accB, 0, 0, 0);
            } else {
                accA = __builtin_amdgcn_mfma_f32_32x32x16_f16(w0, x0, accA, 0, 0, 0);
                accB = __builtin_amdgcn_mfma_f32_32x32x16_f16(w1, x1v, accB, 0, 0, 0);
            }
        }

        if (pr < 2) {
            int o_l = ot * 32 + lm;
            float bv = biasS[q * 64 + o_l];
            #pragma unroll
            for (int r = 0; r < 16; ++r) {
                int p_l = pt * 32 + (r & 3) + 8 * (r >> 2) + 4 * lh;
                Ds[p_l * DQ_STRIDE + o_l] = (f16)(accA[r] + accB[r] + bv);
            }
        } else {
            #pragma unroll
            for (int r = 0; r < 16; ++r) {
                int o_l = ot * 32 + (r & 3) + 8 * (r >> 2) + 4 * lh;
                Ds[o_l * DQ_STRIDE + pt * 32 + lm] =
                    (f16)(accA[r] + accB[r] + biasS[q * 64 + o_l]);
            }
        }
        LBAR();

        #pragma unroll
        for (int j = 0; j < 2; ++j) {
            int row = (t >> 3) + j * 32;
            int cc  = (t & 7) * 8;
            f16x8 vdat = *(const f16x8*)&Ds[row * DQ_STRIDE + cc];
            if (pr < 2) {
                f16* Out = (pr == 0) ? Qg : Kg;
                *(f16x8*)(Out + ((size_t)(b * NPOS + p0 + row)) * CDIM + q * 64 + cc) = vdat;
            } else {
                *(f16x8*)(Vg + ((size_t)(b * CDIM + q * 64 + row)) * NPOS + p0 + cc) = vdat;
            }
        }
        LBAR();
    }
}

// ---------------------------------------------------------------------------
// attn: grid 512, 256 thr = 4 waves, (256,2), 2 blocks/CU, XCD swizzle.
// 2-barrier pipeline per chunk: [Kcommit(i), B1, QK(i), softmax-own(i),
// RedWrite(i), PV(i-1) from V-regs + Pl[prev], issue V(i), B2, merge(i),
// Pwrite(i)]. Epilogue: B + PV(last). LDS 53.2 KB (Ks + dbuf Pl + Red).
// Emits partial F fp32 [bq][half][256c][64p].
// ---------------------------------------------------------------------------
__global__ __launch_bounds__(256, 2) void attn_kernel(
    const f16* __restrict__ Qg, const f16* __restrict__ Kg, const f16* __restrict__ Vg,
    float* __restrict__ Fp)
{
    __shared__ f16   Ks[64 * QK_STRIDE];        // 33792 B  [key][c]
    __shared__ f16   Pl[2][64 * P_STRIDE];      // 18432 B  [p][key]
    __shared__ float RedM[2][64], RedS[2][64];  //  1024 B

    const int t    = threadIdx.x;
    const int L    = (int)((blockIdx.x & 7) * 64 + (blockIdx.x >> 3)); // XCD swizzle
    const int grp  = L >> 6;         // 0..7 = (b<<1 | half)
    const int b    = grp >> 1;
    const int half = grp & 1;
    const int qt   = L & 63;
    const int p0   = qt << 6;
    const int bq   = b * 64 + qt;
    const int w    = t >> 6;         // 0..3
    const int l    = t & 63;
    const int lm   = l & 31;
    const int lh   = l >> 5;
    const int spt  = w & 1;          // wave's p-tile
    const int skt  = w >> 1;         // wave's key-tile

    // Q fragments (MFMA B-operand; layout identical to A-operand)
    f16x8 qf[16];
    {
        const f16* qptr = Qg + (size_t)(b * NPOS + p0 + spt * 32 + lm) * CDIM + lh * 8;
        #pragma unroll
        for (int ks = 0; ks < 16; ++ks) qf[ks] = *(const f16x8*)(qptr + ks * 16);
    }

    // K prefetch registers (rows coalesced from Kg[n][c])
    const int kr = t >> 5, koff = (t & 31) * 8;
    f16x8 kreg[8];
    auto issue_k = [&](int ch) {
        const int i0 = ch * 64;
        #pragma unroll
        for (int r = 0; r < 8; ++r)
            kreg[r] = *(const f16x8*)(Kg + (size_t)(b * NPOS + i0 + r * 8 + kr) * CDIM + koff);
    };
    issue_k(half * 32);

    // V fragment bases (R10's proven reg-PV pattern): wave's c-strip w*64+{0,32}
    const f16* vb0 = Vg + (size_t)(b * CDIM + w * 64 + lm) * NPOS;
    const f16* vb1 = Vg + (size_t)(b * CDIM + w * 64 + 32 + lm) * NPOS;
    f16x8 vfp0[4], vfp1[4];   // V frags of chunk i (consumed by PV in iter i+1)

    f32x16 facc[4] = {};      // per-wave F acc: [ci=c-subtile(2)][pj=p-tile(2)]

    for (int it = 0; it < 32; ++it) {
        const int ch = half * 32 + it;
        const int pb = it & 1;

        // commit prefetched K to LDS, issue next chunk's K loads
        #pragma unroll
        for (int r = 0; r < 8; ++r)
            *(f16x8*)&Ks[(r * 8 + kr) * QK_STRIDE + koff] = kreg[r];
        if (it < 31) issue_k(ch + 1);
        LBAR();   // B1: Ks(it) ready; Pl[pb^1] (Pwrite of it-1) visible

        // S^T = K Q^T : lane holds S^T[16 keys][p = spt*32+lm]
        f32x16 st = {};
        __builtin_amdgcn_s_setprio(1);
        #pragma unroll
        for (int ks = 0; ks < 16; ++ks) {
            f16x8 kf = *(const f16x8*)&Ks[(skt * 32 + lm) * QK_STRIDE + ks * 16 + lh * 8];
            st = __builtin_amdgcn_mfma_f32_32x32x16_f16(kf, qf[ks], st, 0, 0, 0);
        }
        __builtin_amdgcn_s_setprio(0);

        // own-tile softmax reduce (32 keys: 16 own + lh-partner)
        float mx = st[0];
        #pragma unroll
        for (int r = 1; r < 16; ++r) mx = fmaxf(mx, st[r]);
        mx = fmaxf(mx, __shfl_xor(mx, 32));
        float ss = 0.f;
        #pragma unroll
        for (int r = 0; r < 16; ++r) {
            float e = __expf(st[r] - mx);
            st[r] = e;
            ss += e;
        }
        ss += __shfl_xor(ss, 32);
        if (lh == 0) { RedM[skt][spt * 32 + lm] = mx; RedS[skt][spt * 32 + lm] = ss; }

        // PV(it-1): independent of softmax(it) -> MFMA fills VALU gaps
        if (it > 0) {
            const int pp = pb ^ 1;
            __builtin_amdgcn_s_setprio(1);
            #pragma unroll
            for (int kb = 0; kb < 4; ++kb) {
                f16x8 pf0 = *(const f16x8*)&Pl[pp][lm * P_STRIDE + kb * 16 + lh * 8];
                f16x8 pf1 = *(const f16x8*)&Pl[pp][(32 + lm) * P_STRIDE + kb * 16 + lh * 8];
                facc[0] = __builtin_amdgcn_mfma_f32_32x32x16_f16(vfp0[kb], pf0, facc[0], 0, 0, 0);
                facc[1] = __builtin_amdgcn_mfma_f32_32x32x16_f16(vfp0[kb], pf1, facc[1], 0, 0, 0);
                facc[2] = __builtin_amdgcn_mfma_f32_32x32x16_f16(vfp1[kb], pf0, facc[2], 0, 0, 0);
                facc[3] = __builtin_amdgcn_mfma_f32_32x32x16_f16(vfp1[kb], pf1, facc[3], 0, 0, 0);
            }
            __builtin_amdgcn_s_setprio(0);
        }
        // issue this chunk's V fragment loads (consumed by PV next iter)
        {
            const int i0 = ch * 64;
            #pragma unroll
            for (int kb = 0; kb < 4; ++kb) {
                vfp0[kb] = *(const f16x8*)(vb0 + i0 + kb * 16 + lh * 8);
                vfp1[kb] = *(const f16x8*)(vb1 + i0 + kb * 16 + lh * 8);
            }
        }
        LBAR();   // B2: Red ready (V/K globals stay in flight)

        // LSE merge with partner key-tile wave -> full 64-key softmax
        float mo = RedM[skt ^ 1][spt * 32 + lm];
        float so = RedS[skt ^ 1][spt * 32 + lm];
        float M  = fmaxf(mx, mo);
        float S  = ss * __expf(mx - M) + so * __expf(mo - M);
        float scale = __expf(mx - M) * __builtin_amdgcn_rcpf(S);

        // P[key][p] f16 -> Pl[pb][p][key]
        #pragma unroll
        for (int rq = 0; rq < 4; ++rq) {
            f16x4 pk;
            #pragma unroll
            for (int q2 = 0; q2 < 4; ++q2) pk[q2] = (f16)(st[rq * 4 + q2] * scale);
            *(f16x4*)&Pl[pb][(spt * 32 + lm) * P_STRIDE + skt * 32 + rq * 8 + lh * 4] = pk;
        }
    }

    // epilogue: final PV(31)
    LBAR();
    {
        const int pp = 31 & 1;
        #pragma unroll
        for (int kb = 0; kb < 4; ++kb) {
            f16x8 pf0 = *(const f16x8*)&Pl[pp][lm * P_STRIDE + kb * 16 + lh * 8];
            f16x8 pf1 = *(const f16x8*)&Pl[pp][(32 + lm) * P_STRIDE + kb * 16 + lh * 8];
            facc[0] = __builtin_amdgcn_mfma_f32_32x32x16_f16(vfp0[kb], pf0, facc[0], 0, 0, 0);
            facc[1] = __builtin_amdgcn_mfma_f32_32x32x16_f16(vfp0[kb], pf1, facc[1], 0, 0, 0);
            facc[2] = __builtin_amdgcn_mfma_f32_32x32x16_f16(vfp1[kb], pf0, facc[2], 0, 0, 0);
            facc[3] = __builtin_amdgcn_mfma_f32_32x32x16_f16(vfp1[kb], pf1, facc[3], 0, 0, 0);
        }
    }

    // partial F out: Fp[bq][half][c][p] fp32
    float* dst = Fp + ((size_t)bq * 2 + half) * (CDIM * 64);
    #pragma unroll
    for (int ii = 0; ii < 2; ++ii)
        #pragma unroll
        for (int jj = 0; jj < 2; ++jj)
            #pragma unroll
            for (int r = 0; r < 16; ++r) {
                int c = w * 64 + ii * 32 + (r & 3) + 8 * (r >> 2) + 4 * lh;
                int p = jj * 32 + lm;
                dst[c * 64 + p] = facc[ii * 2 + jj][r];
            }
}

// ---------------------------------------------------------------------------
// merge_ln: grid 256 = (b<<6 | qtile), 256 thr. Sums the 2 half-partials
// into LDS, computes per-position mean/var over channels, writes normalized
// output. (unchanged, proven correct)
// ---------------------------------------------------------------------------
__global__ __launch_bounds__(256, 2) void merge_ln_kernel(
    const float* __restrict__ Fp, const float* __restrict__ ln_w,
    const float* __restrict__ ln_b, float* __restrict__ out)
{
    __shared__ float Fs[256 * F_STRIDE];          // 69632 B
    __shared__ float redS[16 * 64], redQ[16 * 64];
    __shared__ float lnw_s[256], lnb_s[256];
    __shared__ float mu_s[64], rs_s[64];

    const int t  = threadIdx.x;
    const int bq = blockIdx.x;
    const int b  = bq >> 6;
    const int p0 = (bq & 63) << 6;

    lnw_s[t] = ln_w[t]; lnb_s[t] = ln_b[t];

    const int pb = (t & 15) * 4;      // 4 consecutive positions
    const int cg = t >> 4;            // 16-channel group
    const float* base = Fp + (size_t)bq * 2 * (CDIM * 64);

    f32x4 s4 = {}, q4 = {};
    #pragma unroll 4
    for (int ci = 0; ci < 16; ++ci) {
        int c = cg * 16 + ci;
        size_t off = (size_t)c * 64 + pb;
        f32x4 v = *(const f32x4*)(base + off);
        v += *(const f32x4*)(base + (size_t)(CDIM * 64) + off);
        *(f32x4*)&Fs[c * F_STRIDE + pb] = v;
        s4 += v; q4 += v * v;
    }
    #pragma unroll
    for (int k2 = 0; k2 < 4; ++k2) {
        redS[cg * 64 + pb + k2] = s4[k2];
        redQ[cg * 64 + pb + k2] = q4[k2];
    }
    __syncthreads();
    if (t < 64) {
        float ss = 0.f, qq = 0.f;
        #pragma unroll
        for (int g2 = 0; g2 < 16; ++g2) { ss += redS[g2 * 64 + t]; qq += redQ[g2 * 64 + t]; }
        float mean = ss * (1.0f / 256.0f);
        float var  = qq * (1.0f / 256.0f) - mean * mean;
        mu_s[t] = mean;
        rs_s[t] = rsqrtf(var + EPSV);
    }
    __syncthreads();
    const int p   = t & 63;
    const int cg2 = t >> 6;
    const float mu = mu_s[p], rs = rs_s[p];
    float* dst = out + (size_t)b * CDIM * NPOS + p0 + p;
    #pragma unroll 4
    for (int ci = 0; ci < 64; ++ci) {
        int c = cg2 * 64 + ci;
        dst[(size_t)c * NPOS] = (Fs[c * F_STRIDE + p] - mu) * rs * lnw_s[c] + lnb_s[c];
    }
}

// ---------------------------------------------------------------------------
extern "C" void kernel_launch(void* const* d_in, const int* in_sizes, int n_in,
                              void* d_out, int out_size, void* d_ws, size_t ws_size,
                              hipStream_t stream)
{
    const float* x1  = (const float*)d_in[0];
    const float* x2  = (const float*)d_in[1];
    const float* qw  = (const float*)d_in[2];
    const float* qb  = (const float*)d_in[3];
    const float* kw  = (const float*)d_in[4];
    const float* kb  = (const float*)d_in[5];
    const float* vw  = (const float*)d_in[6];
    const float* vb  = (const float*)d_in[7];
    const float* lnw = (const float*)d_in[8];
    const float* lnb = (const float*)d_in[9];

    const size_t tsz = (size_t)BATCH * NPOS * CDIM;
    f16* Qg  = (f16*)d_ws;
    f16* Kg  = Qg + tsz;
    f16* Vg  = Kg + tsz;
    f16* W16 = Vg + tsz;                       // 384 KB f16 weights
    float* Fp = (float*)(W16 + 3 * CDIM * CDIM);  // 32 MB fp32; total ws ~57 MB

    wconv_kernel<<<12, 256, 0, stream>>>(qw, kw, vw, W16);
    gemm_kernel<<<768, 256, 0, stream>>>(x1, x2, W16, qb, kb, vb, Qg, Kg, Vg);
    attn_kernel<<<512, 256, 0, stream>>>(Qg, Kg, Vg, Fp);
    merge_ln_kernel<<<256, 256, 0, stream>>>(Fp, lnw, lnb, (float*)d_out);
}

// Round 10
// 214.954 us; speedup vs baseline: 1.0366x; 1.0366x over previous
//
#include <hip/hip_runtime.h>

// B=4, C=256, H=W=64 (N=4096). QKV 1x1conv -> spatial attention (softmax over
// j only => independent per-64-key-chunk softmax) -> channel LayerNorm.
// f16 MFMA 32x32x16, fp32 accumulation.
//
// R16: compose the proven halves of R15's A/B.
// attn: R11/R14 verbatim (measured 105.9/106.4 twice; R12/R13/R15
//   restructures all regressed -> confirmed local optimum). Ks+Vs+Pl LDS
//   staging, swapped QK^T, in-register softmax + LSE merge, 3 LBARs.
// gemm: R15 verbatim (measured -10us vs R14): f16 weights via wconv, Wh
//   register prefetch across rounds, LBAR barriers, fp32-direct Xs staging.
// merge_ln unchanged (proven).

#define CDIM 256
#define NPOS 4096
#define BATCH 4
#define EPSV 1e-5f

typedef _Float16 f16;
typedef __attribute__((ext_vector_type(4))) _Float16 f16x4;
typedef __attribute__((ext_vector_type(8))) _Float16 f16x8;
typedef __attribute__((ext_vector_type(4))) float f32x4;
typedef __attribute__((ext_vector_type(16))) float f32x16;

#define WST       264   // f16; 528B = 33*16 -> b128-aligned rows
#define QK_STRIDE 264   // f16 K-tile rows
#define V_STRIDE  72    // f16 Vs/P rows; 144B = 9*16
#define DQ_STRIDE 72
#define F_STRIDE  68    // merge kernel LDS stride (f32)

// LDS-only barrier: prior LDS ops complete, global loads stay in flight.
#define LBAR() asm volatile("s_waitcnt lgkmcnt(0)\n\ts_barrier" ::: "memory")

// MFMA 32x32x16 f16:
//   A: lane l holds A[m=l&31][k=(l>>5)*8+j]
//   B: lane l holds B[k=(l>>5)*8+j][n=l&31]   (same register layout as A)
//   C/D: lane l, reg r -> row m=(r&3)+8*(r>>2)+4*(l>>5), col n=l&31

static __device__ __forceinline__ f16x8 cvt8(const float* __restrict__ p) {
    float4 w0 = *(const float4*)p;
    float4 w1 = *(const float4*)(p + 4);
    f16x8 r;
    r[0] = (f16)w0.x; r[1] = (f16)w0.y; r[2] = (f16)w0.z; r[3] = (f16)w0.w;
    r[4] = (f16)w1.x; r[5] = (f16)w1.y; r[6] = (f16)w1.z; r[7] = (f16)w1.w;
    return r;
}

// ---------------------------------------------------------------------------
// wconv: 12 blocks convert fp32 weights -> f16 [o][c] (proven).
// ---------------------------------------------------------------------------
__global__ __launch_bounds__(256, 4) void wconv_kernel(
    const float* __restrict__ qw, const float* __restrict__ kw,
    const float* __restrict__ vw, f16* __restrict__ W16)
{
    const int id = blockIdx.x;           // 0..11
    const int t  = threadIdx.x;
    const int pr = id >> 2, h = id & 3;
    const float* W = (pr == 0 ? qw : pr == 1 ? kw : vw) + (size_t)h * 64 * CDIM;
    f16* D = W16 + (size_t)pr * CDIM * CDIM + (size_t)h * 64 * CDIM;
    #pragma unroll
    for (int i = 0; i < 8; ++i) {
        int g = t + i * 256;
        int row = g >> 5, col = (g & 31) * 8;
        *(f16x8*)(D + (size_t)row * CDIM + col) = cvt8(W + (size_t)row * CDIM + col);
    }
}

// ---------------------------------------------------------------------------
// gemm: R15 verbatim (proven -10us). 768 blocks = (pr, b, ptile). Xs staged
// from fp32 x (transpose in LDS staging); Wh staged from f16 W16 with
// cross-round register prefetch; LBAR barriers.
// ---------------------------------------------------------------------------
__global__ __launch_bounds__(256, 2) void gemm_kernel(
    const float* __restrict__ x1, const float* __restrict__ x2,
    const f16* __restrict__ W16,
    const float* __restrict__ qb, const float* __restrict__ kb,
    const float* __restrict__ vb,
    f16* __restrict__ Qg, f16* __restrict__ Kg, f16* __restrict__ Vg)
{
    __shared__ f16 Xs[64 * WST];
    __shared__ f16 Wh[64 * WST];
    __shared__ f16 Ds[64 * DQ_STRIDE];
    __shared__ float biasS[256];

    const int id = blockIdx.x;
    const int pr  = id >> 8;
    const int rem = id & 255;
    const int b   = rem >> 6;
    const int p0  = (rem & 63) << 6;
    const float* xsrc = ((pr == 0) ? x1 : x2) + (size_t)b * CDIM * NPOS + p0;
    const f16* Wp = W16 + (size_t)pr * CDIM * CDIM;
    const float* bias = (pr == 0) ? qb : (pr == 1) ? kb : vb;

    const int t = threadIdx.x, w = t >> 6, l = t & 63, lm = l & 31, lh = l >> 5;
    const int pt = w & 1, ot = w >> 1;

    // W register prefetch (f16, 32 VGPR)
    f16x8 wreg[8];
    auto issue_w = [&](int q) {
        #pragma unroll
        for (int i = 0; i < 8; ++i) {
            int g = t + i * 256;
            int row = g >> 5, col = (g & 31) * 8;
            wreg[i] = *(const f16x8*)(Wp + (size_t)(q * 64 + row) * CDIM + col);
        }
    };
    issue_w(0);

    biasS[t] = bias[t];
    // Xs[p][c] <- x[b][c][p0+p], fp32->f16 (transpose via staging)
    #pragma unroll
    for (int g = 0; g < 8; ++g) {
        f16x8 h;
        #pragma unroll
        for (int j = 0; j < 8; ++j)
            h[j] = (f16)xsrc[(size_t)(w * 64 + g * 8 + j) * NPOS + l];
        *(f16x8*)&Xs[l * WST + w * 64 + g * 8] = h;
    }

    for (int q = 0; q < 4; ++q) {
        // commit prefetched W, then issue next round's W loads
        #pragma unroll
        for (int i = 0; i < 8; ++i) {
            int g = t + i * 256;
            int row = g >> 5, col = (g & 31) * 8;
            *(f16x8*)&Wh[row * WST + col] = wreg[i];
        }
        if (q < 3) issue_w(q + 1);
        LBAR();

        f32x16 accA = {}, accB = {};
        #pragma unroll
        for (int ks = 0; ks < 16; ks += 2) {
            f16x8 x0 = *(const f16x8*)&Xs[(pt * 32 + lm) * WST + ks * 16 + lh * 8];
            f16x8 w0 = *(const f16x8*)&Wh[(ot * 32 + lm) * WST + ks * 16 + lh * 8];
            f16x8 x1v = *(const f16x8*)&Xs[(pt * 32 + lm) * WST + (ks + 1) * 16 + lh * 8];
            f16x8 w1 = *(const f16x8*)&Wh[(ot * 32 + lm) * WST + (ks + 1) * 16 + lh * 8];
            if (pr < 2) {
                accA = __builtin_amdgcn_mfma_f32_32x32x16_f16(x0, w0, accA, 0, 0, 0);
                accB = __builtin_amdgcn_mfma_f32_32x32x16_f16(x1v, w1, accB, 0, 0, 0);
            } else {
                accA = __builtin_amdgcn_mfma_f32_32x32x16_f16(w0, x0, accA, 0, 0, 0);
                accB = __builtin_amdgcn_mfma_f32_32x32x16_f16(w1, x1v, accB, 0, 0, 0);
            }
        }

        if (pr < 2) {
            int o_l = ot * 32 + lm;
            float bv = biasS[q * 64 + o_l];
            #pragma unroll
            for (int r = 0; r < 16; ++r) {
                int p_l = pt * 32 + (r & 3) + 8 * (r >> 2) + 4 * lh;
                Ds[p_l * DQ_STRIDE + o_l] = (f16)(accA[r] + accB[r] + bv);
            }
        } else {
            #pragma unroll
            for (int r = 0; r < 16; ++r) {
                int o_l = ot * 32 + (r & 3) + 8 * (r >> 2) + 4 * lh;
                Ds[o_l * DQ_STRIDE + pt * 32 + lm] =
                    (f16)(accA[r] + accB[r] + biasS[q * 64 + o_l]);
            }
        }
        LBAR();

        #pragma unroll
        for (int j = 0; j < 2; ++j) {
            int row = (t >> 3) + j * 32;
            int cc  = (t & 7) * 8;
            f16x8 vdat = *(const f16x8*)&Ds[row * DQ_STRIDE + cc];
            if (pr < 2) {
                f16* Out = (pr == 0) ? Qg : Kg;
                *(f16x8*)(Out + ((size_t)(b * NPOS + p0 + row)) * CDIM + q * 64 + cc) = vdat;
            } else {
                *(f16x8*)(Vg + ((size_t)(b * CDIM + q * 64 + row)) * NPOS + p0 + cc) = vdat;
            }
        }
        LBAR();
    }
}

// ---------------------------------------------------------------------------
// attn: R11/R14 verbatim (proven 105.9/106.4). grid 512, 256 thr = 4 waves,
// (256,2), 2 blocks/CU co-resident, bijective XCD swizzle. Per chunk: K+V
// reg-prefetch -> LDS commit; swapped QK^T (S^T in registers); in-register
// softmax with LSE cross-wave merge; P f16 tile -> LDS; PV from Vs+P
// ds_read_b128. 3 LDS-only barriers. Partial F fp32 [bq][half][256c][64p].
// ---------------------------------------------------------------------------
__global__ __launch_bounds__(256, 2) void attn_kernel(
    const f16* __restrict__ Qg, const f16* __restrict__ Kg, const f16* __restrict__ Vg,
    float* __restrict__ Fp)
{
    __shared__ f16   Ks[64 * QK_STRIDE];   // 33792 B  [key][c]
    __shared__ f16   Vs[256 * V_STRIDE];   // 36864 B  [c][j]
    __shared__ f16   Pl[64 * V_STRIDE];    //  9216 B  [p][key]
    __shared__ float RedM[2][64], RedS[2][64];  // 1024 B

    const int t    = threadIdx.x;
    const int L    = (int)((blockIdx.x & 7) * 64 + (blockIdx.x >> 3)); // XCD swizzle
    const int grp  = L >> 6;         // 0..7 = (b<<1 | half)
    const int b    = grp >> 1;
    const int half = grp & 1;
    const int qt   = L & 63;
    const int p0   = qt << 6;
    const int bq   = b * 64 + qt;
    const int w    = t >> 6;         // 0..3
    const int l    = t & 63;
    const int lm   = l & 31;
    const int lh   = l >> 5;
    const int spt  = w & 1;          // wave's p-tile
    const int skt  = w >> 1;         // wave's key-tile

    // Q fragments (MFMA B-operand; layout identical to A-operand)
    f16x8 qf[16];
    {
        const f16* qptr = Qg + (size_t)(b * NPOS + p0 + spt * 32 + lm) * CDIM + lh * 8;
        #pragma unroll
        for (int ks = 0; ks < 16; ++ks) qf[ks] = *(const f16x8*)(qptr + ks * 16);
    }

    // K prefetch registers (rows coalesced from Kg[n][c])
    const int kr = t >> 5, koff = (t & 31) * 8;
    f16x8 kreg[8];
    auto issue_k = [&](int ch) {
        const int i0 = ch * 64;
        #pragma unroll
        for (int r = 0; r < 8; ++r)
            kreg[r] = *(const f16x8*)(Kg + (size_t)(b * NPOS + i0 + r * 8 + kr) * CDIM + koff);
    };

    // V prefetch registers (128B-contiguous runs per c-row from Vg[c][n])
    const int vr = t >> 3;           // c row within each 32-row group
    const int vc = (t & 7) * 8;      // halfword col within chunk
    f16x8 vreg[8];
    auto issue_v = [&](int ch) {
        const int i0 = ch * 64;
        #pragma unroll
        for (int i = 0; i < 8; ++i)
            vreg[i] = *(const f16x8*)(Vg + (size_t)(b * CDIM + i * 32 + vr) * NPOS + i0 + vc);
    };

    issue_k(half * 32);
    issue_v(half * 32);

    f32x16 facc[4] = {};      // per-wave F acc: [ci=c-subtile(2)][pj=p-tile(2)]

    for (int it = 0; it < 32; ++it) {
        const int ch = half * 32 + it;

        // commit prefetched K to LDS, then issue next chunk's K loads
        #pragma unroll
        for (int r = 0; r < 8; ++r)
            *(f16x8*)&Ks[(r * 8 + kr) * QK_STRIDE + koff] = kreg[r];
        if (it < 31) issue_k(ch + 1);
        LBAR();   // A: Ks ready; prev PV's Vs/Pl reads done

        // commit prefetched V to LDS, then issue next chunk's V loads
        #pragma unroll
        for (int i = 0; i < 8; ++i)
            *(f16x8*)&Vs[(i * 32 + vr) * V_STRIDE + vc] = vreg[i];
        if (it < 31) issue_v(ch + 1);

        // S^T = K Q^T : D[m=key][n=p]; lane holds S^T[16 keys][p=spt*32+lm]
        f32x16 st = {};
        __builtin_amdgcn_s_setprio(1);
        #pragma unroll
        for (int ks = 0; ks < 16; ++ks) {
            f16x8 kf = *(const f16x8*)&Ks[(skt * 32 + lm) * QK_STRIDE + ks * 16 + lh * 8];
            st = __builtin_amdgcn_mfma_f32_32x32x16_f16(kf, qf[ks], st, 0, 0, 0);
        }
        __builtin_amdgcn_s_setprio(0);

        // in-register softmax over this key-tile (32 keys: 16 own + lh-partner)
        float mx = st[0];
        #pragma unroll
        for (int r = 1; r < 16; ++r) mx = fmaxf(mx, st[r]);
        mx = fmaxf(mx, __shfl_xor(mx, 32));
        float ss = 0.f;
        #pragma unroll
        for (int r = 0; r < 16; ++r) {
            float e = __expf(st[r] - mx);
            st[r] = e;
            ss += e;
        }
        ss += __shfl_xor(ss, 32);
        if (lh == 0) { RedM[skt][spt * 32 + lm] = mx; RedS[skt][spt * 32 + lm] = ss; }
        LBAR();   // B: Red exchange ready

        // LSE merge with partner key-tile wave -> full 64-key softmax
        float mo = RedM[skt ^ 1][spt * 32 + lm];
        float so = RedS[skt ^ 1][spt * 32 + lm];
        float M  = fmaxf(mx, mo);
        float S  = ss * __expf(mx - M) + so * __expf(mo - M);
        float scale = __expf(mx - M) * __builtin_amdgcn_rcpf(S);

        // P[key][p] f16 -> Pl[p][key]; lane's 16 keys = 4 runs of 4 consecutive
        #pragma unroll
        for (int rq = 0; rq < 4; ++rq) {
            f16x4 pk;
            #pragma unroll
            for (int q2 = 0; q2 < 4; ++q2) pk[q2] = (f16)(st[rq * 4 + q2] * scale);
            *(f16x4*)&Pl[(spt * 32 + lm) * V_STRIDE + skt * 32 + rq * 8 + lh * 4] = pk;
        }
        LBAR();   // C: Pl ready; Vs commits drained

        // F += V P : D[m=c][n=p]; A=Vs rows, B=Pl rows (both b128-contiguous)
        __builtin_amdgcn_s_setprio(1);
        #pragma unroll
        for (int kb = 0; kb < 4; ++kb) {
            f16x8 pf0 = *(const f16x8*)&Pl[lm * V_STRIDE + kb * 16 + lh * 8];
            f16x8 pf1 = *(const f16x8*)&Pl[(32 + lm) * V_STRIDE + kb * 16 + lh * 8];
            f16x8 va0 = *(const f16x8*)&Vs[(w * 64 + lm) * V_STRIDE + kb * 16 + lh * 8];
            f16x8 va1 = *(const f16x8*)&Vs[(w * 64 + 32 + lm) * V_STRIDE + kb * 16 + lh * 8];
            facc[0] = __builtin_amdgcn_mfma_f32_32x32x16_f16(va0, pf0, facc[0], 0, 0, 0);
            facc[1] = __builtin_amdgcn_mfma_f32_32x32x16_f16(va0, pf1, facc[1], 0, 0, 0);
            facc[2] = __builtin_amdgcn_mfma_f32_32x32x16_f16(va1, pf0, facc[2], 0, 0, 0);
            facc[3] = __builtin_amdgcn_mfma_f32_32x32x16_f16(va1, pf1, facc[3], 0, 0, 0);
        }
        __builtin_amdgcn_s_setprio(0);
    }

    // partial F out: Fp[bq][half][c][p] fp32
    float* dst = Fp + ((size_t)bq * 2 + half) * (CDIM * 64);
    #pragma unroll
    for (int ii = 0; ii < 2; ++ii)
        #pragma unroll
        for (int jj = 0; jj < 2; ++jj)
            #pragma unroll
            for (int r = 0; r < 16; ++r) {
                int c = w * 64 + ii * 32 + (r & 3) + 8 * (r >> 2) + 4 * lh;
                int p = jj * 32 + lm;
                dst[c * 64 + p] = facc[ii * 2 + jj][r];
            }
}

// ---------------------------------------------------------------------------
// merge_ln: grid 256 = (b<<6 | qtile), 256 thr. Sums the 2 half-partials
// into LDS, computes per-position mean/var over channels, writes normalized
// output. (unchanged, proven correct)
// ---------------------------------------------------------------------------
__global__ __launch_bounds__(256, 2) void merge_ln_kernel(
    const float* __restrict__ Fp, const float* __restrict__ ln_w,
    const float* __restrict__ ln_b, float* __restrict__ out)
{
    __shared__ float Fs[256 * F_STRIDE];          // 69632 B
    __shared__ float redS[16 * 64], redQ[16 * 64];
    __shared__ float lnw_s[256], lnb_s[256];
    __shared__ float mu_s[64], rs_s[64];

    const int t  = threadIdx.x;
    const int bq = blockIdx.x;
    const int b  = bq >> 6;
    const int p0 = (bq & 63) << 6;

    lnw_s[t] = ln_w[t]; lnb_s[t] = ln_b[t];

    const int pb = (t & 15) * 4;      // 4 consecutive positions
    const int cg = t >> 4;            // 16-channel group
    const float* base = Fp + (size_t)bq * 2 * (CDIM * 64);

    f32x4 s4 = {}, q4 = {};
    #pragma unroll 4
    for (int ci = 0; ci < 16; ++ci) {
        int c = cg * 16 + ci;
        size_t off = (size_t)c * 64 + pb;
        f32x4 v = *(const f32x4*)(base + off);
        v += *(const f32x4*)(base + (size_t)(CDIM * 64) + off);
        *(f32x4*)&Fs[c * F_STRIDE + pb] = v;
        s4 += v; q4 += v * v;
    }
    #pragma unroll
    for (int k2 = 0; k2 < 4; ++k2) {
        redS[cg * 64 + pb + k2] = s4[k2];
        redQ[cg * 64 + pb + k2] = q4[k2];
    }
    __syncthreads();
    if (t < 64) {
        float ss = 0.f, qq = 0.f;
        #pragma unroll
        for (int g2 = 0; g2 < 16; ++g2) { ss += redS[g2 * 64 + t]; qq += redQ[g2 * 64 + t]; }
        float mean = ss * (1.0f / 256.0f);
        float var  = qq * (1.0f / 256.0f) - mean * mean;
        mu_s[t] = mean;
        rs_s[t] = rsqrtf(var + EPSV);
    }
    __syncthreads();
    const int p   = t & 63;
    const int cg2 = t >> 6;
    const float mu = mu_s[p], rs = rs_s[p];
    float* dst = out + (size_t)b * CDIM * NPOS + p0 + p;
    #pragma unroll 4
    for (int ci = 0; ci < 64; ++ci) {
        int c = cg2 * 64 + ci;
        dst[(size_t)c * NPOS] = (Fs[c * F_STRIDE + p] - mu) * rs * lnw_s[c] + lnb_s[c];
    }
}

// ---------------------------------------------------------------------------
extern "C" void kernel_launch(void* const* d_in, const int* in_sizes, int n_in,
                              void* d_out, int out_size, void* d_ws, size_t ws_size,
                              hipStream_t stream)
{
    const float* x1  = (const float*)d_in[0];
    const float* x2  = (const float*)d_in[1];
    const float* qw  = (const float*)d_in[2];
    const float* qb  = (const float*)d_in[3];
    const float* kw  = (const float*)d_in[4];
    const float* kb  = (const float*)d_in[5];
    const float* vw  = (const float*)d_in[6];
    const float* vb  = (const float*)d_in[7];
    const float* lnw = (const float*)d_in[8];
    const float* lnb = (const float*)d_in[9];

    const size_t tsz = (size_t)BATCH * NPOS * CDIM;
    f16* Qg  = (f16*)d_ws;
    f16* Kg  = Qg + tsz;
    f16* Vg  = Kg + tsz;
    f16* W16 = Vg + tsz;                          // 384 KB f16 weights
    float* Fp = (float*)(W16 + 3 * CDIM * CDIM);  // 32 MB fp32; total ws ~57 MB

    wconv_kernel<<<12, 256, 0, stream>>>(qw, kw, vw, W16);
    gemm_kernel<<<768, 256, 0, stream>>>(x1, x2, W16, qb, kb, vb, Qg, Kg, Vg);
    attn_kernel<<<512, 256, 0, stream>>>(Qg, Kg, Vg, Fp);
    merge_ln_kernel<<<256, 256, 0, stream>>>(Fp, lnw, lnb, (float*)d_out);
}

// Round 11
// 210.557 us; speedup vs baseline: 1.0582x; 1.0209x over previous
//
#include <hip/hip_runtime.h>

// B=4, C=256, H=W=64 (N=4096). QKV 1x1conv -> spatial attention (softmax over
// j only => independent per-64-key-chunk softmax) -> channel LayerNorm.
// f16 MFMA, fp32 accumulation.
//
// R17: surgical change inside the proven R11/R16 attn loop: QK^T re-tiled to
// mfma_f32_16x16x32_f16. Each wave now computes S^T[all 64 keys][16 own p]
// (4 key m-tiles x 8 k-steps = 32 MFMAs, 4 independent acc chains vs one
// 16-deep). C/D col=lane&15 -> lanes l,l^16,l^32,l^48 share a p-column and
// jointly hold all 64 keys: full softmax = 2 shfl_xor reduces IN-WAVE.
// Deletes: barrier B, RedM/RedS exchange, LSE merge (one barrier + a serial
// VALU phase off the chunk critical path). qf 64->32 VGPR. Ks/Vs/Pl staging,
// K/V reg-prefetch, PV (32x32x16), partial-F layout: byte-for-byte R16.
// gemm/wconv/merge_ln: R16 verbatim (proven).

#define CDIM 256
#define NPOS 4096
#define BATCH 4
#define EPSV 1e-5f

typedef _Float16 f16;
typedef __attribute__((ext_vector_type(4))) _Float16 f16x4;
typedef __attribute__((ext_vector_type(8))) _Float16 f16x8;
typedef __attribute__((ext_vector_type(4))) float f32x4;
typedef __attribute__((ext_vector_type(16))) float f32x16;

#define WST       264   // f16; 528B = 33*16 -> b128-aligned rows
#define QK_STRIDE 264   // f16 K-tile rows
#define V_STRIDE  72    // f16 Vs/P rows; 144B = 9*16
#define DQ_STRIDE 72
#define F_STRIDE  68    // merge kernel LDS stride (f32)

// LDS-only barrier: prior LDS ops complete, global loads stay in flight.
#define LBAR() asm volatile("s_waitcnt lgkmcnt(0)\n\ts_barrier" ::: "memory")

// MFMA 32x32x16 f16:
//   A: lane l holds A[m=l&31][k=(l>>5)*8+j]
//   B: lane l holds B[k=(l>>5)*8+j][n=l&31]
//   C/D: lane l, reg r -> row m=(r&3)+8*(r>>2)+4*(l>>5), col n=l&31
// MFMA 16x16x32 f16 (same pattern, 16-row tiles, 4 k-groups):
//   A: lane l holds A[m=l&15][k=(l>>4)*8+j]
//   B: lane l holds B[k=(l>>4)*8+j][n=l&15]
//   C/D: lane l, reg r -> row m=(l>>4)*4+r, col n=l&15

static __device__ __forceinline__ f16x8 cvt8(const float* __restrict__ p) {
    float4 w0 = *(const float4*)p;
    float4 w1 = *(const float4*)(p + 4);
    f16x8 r;
    r[0] = (f16)w0.x; r[1] = (f16)w0.y; r[2] = (f16)w0.z; r[3] = (f16)w0.w;
    r[4] = (f16)w1.x; r[5] = (f16)w1.y; r[6] = (f16)w1.z; r[7] = (f16)w1.w;
    return r;
}

// ---------------------------------------------------------------------------
// wconv: 12 blocks convert fp32 weights -> f16 [o][c] (proven).
// ---------------------------------------------------------------------------
__global__ __launch_bounds__(256, 4) void wconv_kernel(
    const float* __restrict__ qw, const float* __restrict__ kw,
    const float* __restrict__ vw, f16* __restrict__ W16)
{
    const int id = blockIdx.x;           // 0..11
    const int t  = threadIdx.x;
    const int pr = id >> 2, h = id & 3;
    const float* W = (pr == 0 ? qw : pr == 1 ? kw : vw) + (size_t)h * 64 * CDIM;
    f16* D = W16 + (size_t)pr * CDIM * CDIM + (size_t)h * 64 * CDIM;
    #pragma unroll
    for (int i = 0; i < 8; ++i) {
        int g = t + i * 256;
        int row = g >> 5, col = (g & 31) * 8;
        *(f16x8*)(D + (size_t)row * CDIM + col) = cvt8(W + (size_t)row * CDIM + col);
    }
}

// ---------------------------------------------------------------------------
// gemm: R16 verbatim (proven). Xs staged from fp32 x (transpose in staging);
// Wh staged from f16 W16 with cross-round register prefetch; LBAR barriers.
// ---------------------------------------------------------------------------
__global__ __launch_bounds__(256, 2) void gemm_kernel(
    const float* __restrict__ x1, const float* __restrict__ x2,
    const f16* __restrict__ W16,
    const float* __restrict__ qb, const float* __restrict__ kb,
    const float* __restrict__ vb,
    f16* __restrict__ Qg, f16* __restrict__ Kg, f16* __restrict__ Vg)
{
    __shared__ f16 Xs[64 * WST];
    __shared__ f16 Wh[64 * WST];
    __shared__ f16 Ds[64 * DQ_STRIDE];
    __shared__ float biasS[256];

    const int id = blockIdx.x;
    const int pr  = id >> 8;
    const int rem = id & 255;
    const int b   = rem >> 6;
    const int p0  = (rem & 63) << 6;
    const float* xsrc = ((pr == 0) ? x1 : x2) + (size_t)b * CDIM * NPOS + p0;
    const f16* Wp = W16 + (size_t)pr * CDIM * CDIM;
    const float* bias = (pr == 0) ? qb : (pr == 1) ? kb : vb;

    const int t = threadIdx.x, w = t >> 6, l = t & 63, lm = l & 31, lh = l >> 5;
    const int pt = w & 1, ot = w >> 1;

    // W register prefetch (f16, 32 VGPR)
    f16x8 wreg[8];
    auto issue_w = [&](int q) {
        #pragma unroll
        for (int i = 0; i < 8; ++i) {
            int g = t + i * 256;
            int row = g >> 5, col = (g & 31) * 8;
            wreg[i] = *(const f16x8*)(Wp + (size_t)(q * 64 + row) * CDIM + col);
        }
    };
    issue_w(0);

    biasS[t] = bias[t];
    // Xs[p][c] <- x[b][c][p0+p], fp32->f16 (transpose via staging)
    #pragma unroll
    for (int g = 0; g < 8; ++g) {
        f16x8 h;
        #pragma unroll
        for (int j = 0; j < 8; ++j)
            h[j] = (f16)xsrc[(size_t)(w * 64 + g * 8 + j) * NPOS + l];
        *(f16x8*)&Xs[l * WST + w * 64 + g * 8] = h;
    }

    for (int q = 0; q < 4; ++q) {
        // commit prefetched W, then issue next round's W loads
        #pragma unroll
        for (int i = 0; i < 8; ++i) {
            int g = t + i * 256;
            int row = g >> 5, col = (g & 31) * 8;
            *(f16x8*)&Wh[row * WST + col] = wreg[i];
        }
        if (q < 3) issue_w(q + 1);
        LBAR();

        f32x16 accA = {}, accB = {};
        #pragma unroll
        for (int ks = 0; ks < 16; ks += 2) {
            f16x8 x0 = *(const f16x8*)&Xs[(pt * 32 + lm) * WST + ks * 16 + lh * 8];
            f16x8 w0 = *(const f16x8*)&Wh[(ot * 32 + lm) * WST + ks * 16 + lh * 8];
            f16x8 x1v = *(const f16x8*)&Xs[(pt * 32 + lm) * WST + (ks + 1) * 16 + lh * 8];
            f16x8 w1 = *(const f16x8*)&Wh[(ot * 32 + lm) * WST + (ks + 1) * 16 + lh * 8];
            if (pr < 2) {
                accA = __builtin_amdgcn_mfma_f32_32x32x16_f16(x0, w0, accA, 0, 0, 0);
                accB = __builtin_amdgcn_mfma_f32_32x32x16_f16(x1v, w1, accB, 0, 0, 0);
            } else {
                accA = __builtin_amdgcn_mfma_f32_32x32x16_f16(w0, x0, accA, 0, 0, 0);
                accB = __builtin_amdgcn_mfma_f32_32x32x16_f16(w1, x1v, accB, 0, 0, 0);
            }
        }

        if (pr < 2) {
            int o_l = ot * 32 + lm;
            float bv = biasS[q * 64 + o_l];
            #pragma unroll
            for (int r = 0; r < 16; ++r) {
                int p_l = pt * 32 + (r & 3) + 8 * (r >> 2) + 4 * lh;
                Ds[p_l * DQ_STRIDE + o_l] = (f16)(accA[r] + accB[r] + bv);
            }
        } else {
            #pragma unroll
            for (int r = 0; r < 16; ++r) {
                int o_l = ot * 32 + (r & 3) + 8 * (r >> 2) + 4 * lh;
                Ds[o_l * DQ_STRIDE + pt * 32 + lm] =
                    (f16)(accA[r] + accB[r] + biasS[q * 64 + o_l]);
            }
        }
        LBAR();

        #pragma unroll
        for (int j = 0; j < 2; ++j) {
            int row = (t >> 3) + j * 32;
            int cc  = (t & 7) * 8;
            f16x8 vdat = *(const f16x8*)&Ds[row * DQ_STRIDE + cc];
            if (pr < 2) {
                f16* Out = (pr == 0) ? Qg : Kg;
                *(f16x8*)(Out + ((size_t)(b * NPOS + p0 + row)) * CDIM + q * 64 + cc) = vdat;
            } else {
                *(f16x8*)(Vg + ((size_t)(b * CDIM + q * 64 + row)) * NPOS + p0 + cc) = vdat;
            }
        }
        LBAR();
    }
}

// ---------------------------------------------------------------------------
// attn: grid 512, 256 thr = 4 waves, (256,2), 2 blocks/CU, XCD swizzle.
// Per chunk: K+V reg-prefetch -> LDS commit; QK^T via 16x16x32 MFMA (wave =
// all 64 keys x 16 own p, 4 indep chains); FULL in-wave softmax (2 shfl_xor);
// P -> Pl; PV in 32x32x16 from Vs+Pl. 2 LDS-only barriers per chunk.
// Emits partial F fp32 [bq][half][256c][64p].
// ---------------------------------------------------------------------------
__global__ __launch_bounds__(256, 2) void attn_kernel(
    const f16* __restrict__ Qg, const f16* __restrict__ Kg, const f16* __restrict__ Vg,
    float* __restrict__ Fp)
{
    __shared__ f16   Ks[64 * QK_STRIDE];   // 33792 B  [key][c]
    __shared__ f16   Vs[256 * V_STRIDE];   // 36864 B  [c][j]
    __shared__ f16   Pl[64 * V_STRIDE];    //  9216 B  [p][key]

    const int t    = threadIdx.x;
    const int L    = (int)((blockIdx.x & 7) * 64 + (blockIdx.x >> 3)); // XCD swizzle
    const int grp  = L >> 6;         // 0..7 = (b<<1 | half)
    const int b    = grp >> 1;
    const int half = grp & 1;
    const int qt   = L & 63;
    const int p0   = qt << 6;
    const int bq   = b * 64 + qt;
    const int w    = t >> 6;         // 0..3
    const int l    = t & 63;
    const int lm   = l & 31;
    const int lh   = l >> 5;
    const int l4   = l & 15;         // 16x16 tile col (p within wave's 16)
    const int kg   = l >> 4;         // 16x16 k-group / key subgroup

    // Q fragments for 16x16x32 B-operand: lane covers Q[p = p0+w*16+l4]
    // [c = ks*32 + kg*8 + 0..7], ks = 0..7.  (32 VGPR)
    f16x8 qf[8];
    {
        const f16* qptr = Qg + (size_t)(b * NPOS + p0 + w * 16 + l4) * CDIM + kg * 8;
        #pragma unroll
        for (int ks = 0; ks < 8; ++ks) qf[ks] = *(const f16x8*)(qptr + ks * 32);
    }

    // K prefetch registers (rows coalesced from Kg[n][c])
    const int kr = t >> 5, koff = (t & 31) * 8;
    f16x8 kreg[8];
    auto issue_k = [&](int ch) {
        const int i0 = ch * 64;
        #pragma unroll
        for (int r = 0; r < 8; ++r)
            kreg[r] = *(const f16x8*)(Kg + (size_t)(b * NPOS + i0 + r * 8 + kr) * CDIM + koff);
    };

    // V prefetch registers (128B-contiguous runs per c-row from Vg[c][n])
    const int vr = t >> 3;           // c row within each 32-row group
    const int vc = (t & 7) * 8;      // halfword col within chunk
    f16x8 vreg[8];
    auto issue_v = [&](int ch) {
        const int i0 = ch * 64;
        #pragma unroll
        for (int i = 0; i < 8; ++i)
            vreg[i] = *(const f16x8*)(Vg + (size_t)(b * CDIM + i * 32 + vr) * NPOS + i0 + vc);
    };

    issue_k(half * 32);
    issue_v(half * 32);

    f32x16 facc[4] = {};      // per-wave F acc: [ci=c-subtile(2)][pj=p-tile(2)]

    for (int it = 0; it < 32; ++it) {
        const int ch = half * 32 + it;

        // commit prefetched K to LDS, then issue next chunk's K loads
        #pragma unroll
        for (int r = 0; r < 8; ++r)
            *(f16x8*)&Ks[(r * 8 + kr) * QK_STRIDE + koff] = kreg[r];
        if (it < 31) issue_k(ch + 1);
        LBAR();   // A: Ks ready; prev PV's Vs/Pl reads done

        // commit prefetched V to LDS, then issue next chunk's V loads
        #pragma unroll
        for (int i = 0; i < 8; ++i)
            *(f16x8*)&Vs[(i * 32 + vr) * V_STRIDE + vc] = vreg[i];
        if (it < 31) issue_v(ch + 1);

        // S^T = K Q^T via 16x16x32: st[t] covers keys t*16+kg*4+r, p=w*16+l4.
        // 4 independent accumulator chains of depth 8.
        f32x4 st[4] = {};
        __builtin_amdgcn_s_setprio(1);
        #pragma unroll
        for (int ks = 0; ks < 8; ++ks) {
            #pragma unroll
            for (int kt = 0; kt < 4; ++kt) {
                f16x8 kf = *(const f16x8*)&Ks[(kt * 16 + l4) * QK_STRIDE + ks * 32 + kg * 8];
                st[kt] = __builtin_amdgcn_mfma_f32_16x16x32_f16(kf, qf[ks], st[kt], 0, 0, 0);
            }
        }
        __builtin_amdgcn_s_setprio(0);

        // FULL in-wave softmax over 64 keys: lane holds 16; partners l^16,l^32
        // hold the rest of this p-column.
        float mx = st[0][0];
        #pragma unroll
        for (int kt = 0; kt < 4; ++kt)
            #pragma unroll
            for (int r = 0; r < 4; ++r) mx = fmaxf(mx, st[kt][r]);
        mx = fmaxf(mx, __shfl_xor(mx, 16));
        mx = fmaxf(mx, __shfl_xor(mx, 32));
        float ss = 0.f;
        #pragma unroll
        for (int kt = 0; kt < 4; ++kt)
            #pragma unroll
            for (int r = 0; r < 4; ++r) {
                float e = __expf(st[kt][r] - mx);
                st[kt][r] = e;
                ss += e;
            }
        ss += __shfl_xor(ss, 16);
        ss += __shfl_xor(ss, 32);
        float inv = __builtin_amdgcn_rcpf(ss);

        // P -> Pl[p][key]: lane writes 4x f16x4 (keys kt*16+kg*4 .. +3)
        #pragma unroll
        for (int kt = 0; kt < 4; ++kt) {
            f16x4 pk;
            #pragma unroll
            for (int r = 0; r < 4; ++r) pk[r] = (f16)(st[kt][r] * inv);
            *(f16x4*)&Pl[(w * 16 + l4) * V_STRIDE + kt * 16 + kg * 4] = pk;
        }
        LBAR();   // C: Pl ready; Vs commits drained

        // F += V P : D[m=c][n=p]; A=Vs rows, B=Pl rows (both b128-contiguous)
        __builtin_amdgcn_s_setprio(1);
        #pragma unroll
        for (int kb = 0; kb < 4; ++kb) {
            f16x8 pf0 = *(const f16x8*)&Pl[lm * V_STRIDE + kb * 16 + lh * 8];
            f16x8 pf1 = *(const f16x8*)&Pl[(32 + lm) * V_STRIDE + kb * 16 + lh * 8];
            f16x8 va0 = *(const f16x8*)&Vs[(w * 64 + lm) * V_STRIDE + kb * 16 + lh * 8];
            f16x8 va1 = *(const f16x8*)&Vs[(w * 64 + 32 + lm) * V_STRIDE + kb * 16 + lh * 8];
            facc[0] = __builtin_amdgcn_mfma_f32_32x32x16_f16(va0, pf0, facc[0], 0, 0, 0);
            facc[1] = __builtin_amdgcn_mfma_f32_32x32x16_f16(va0, pf1, facc[1], 0, 0, 0);
            facc[2] = __builtin_amdgcn_mfma_f32_32x32x16_f16(va1, pf0, facc[2], 0, 0, 0);
            facc[3] = __builtin_amdgcn_mfma_f32_32x32x16_f16(va1, pf1, facc[3], 0, 0, 0);
        }
        __builtin_amdgcn_s_setprio(0);
    }

    // partial F out: Fp[bq][half][c][p] fp32 (unchanged layout)
    float* dst = Fp + ((size_t)bq * 2 + half) * (CDIM * 64);
    #pragma unroll
    for (int ii = 0; ii < 2; ++ii)
        #pragma unroll
        for (int jj = 0; jj < 2; ++jj)
            #pragma unroll
            for (int r = 0; r < 16; ++r) {
                int c = w * 64 + ii * 32 + (r & 3) + 8 * (r >> 2) + 4 * lh;
                int p = jj * 32 + lm;
                dst[c * 64 + p] = facc[ii * 2 + jj][r];
            }
}

// ---------------------------------------------------------------------------
// merge_ln: grid 256 = (b<<6 | qtile), 256 thr. Sums the 2 half-partials
// into LDS, computes per-position mean/var over channels, writes normalized
// output. (unchanged, proven correct)
// ---------------------------------------------------------------------------
__global__ __launch_bounds__(256, 2) void merge_ln_kernel(
    const float* __restrict__ Fp, const float* __restrict__ ln_w,
    const float* __restrict__ ln_b, float* __restrict__ out)
{
    __shared__ float Fs[256 * F_STRIDE];          // 69632 B
    __shared__ float redS[16 * 64], redQ[16 * 64];
    __shared__ float lnw_s[256], lnb_s[256];
    __shared__ float mu_s[64], rs_s[64];

    const int t  = threadIdx.x;
    const int bq = blockIdx.x;
    const int b  = bq >> 6;
    const int p0 = (bq & 63) << 6;

    lnw_s[t] = ln_w[t]; lnb_s[t] = ln_b[t];

    const int pb = (t & 15) * 4;      // 4 consecutive positions
    const int cg = t >> 4;            // 16-channel group
    const float* base = Fp + (size_t)bq * 2 * (CDIM * 64);

    f32x4 s4 = {}, q4 = {};
    #pragma unroll 4
    for (int ci = 0; ci < 16; ++ci) {
        int c = cg * 16 + ci;
        size_t off = (size_t)c * 64 + pb;
        f32x4 v = *(const f32x4*)(base + off);
        v += *(const f32x4*)(base + (size_t)(CDIM * 64) + off);
        *(f32x4*)&Fs[c * F_STRIDE + pb] = v;
        s4 += v; q4 += v * v;
    }
    #pragma unroll
    for (int k2 = 0; k2 < 4; ++k2) {
        redS[cg * 64 + pb + k2] = s4[k2];
        redQ[cg * 64 + pb + k2] = q4[k2];
    }
    __syncthreads();
    if (t < 64) {
        float ss = 0.f, qq = 0.f;
        #pragma unroll
        for (int g2 = 0; g2 < 16; ++g2) { ss += redS[g2 * 64 + t]; qq += redQ[g2 * 64 + t]; }
        float mean = ss * (1.0f / 256.0f);
        float var  = qq * (1.0f / 256.0f) - mean * mean;
        mu_s[t] = mean;
        rs_s[t] = rsqrtf(var + EPSV);
    }
    __syncthreads();
    const int p   = t & 63;
    const int cg2 = t >> 6;
    const float mu = mu_s[p], rs = rs_s[p];
    float* dst = out + (size_t)b * CDIM * NPOS + p0 + p;
    #pragma unroll 4
    for (int ci = 0; ci < 64; ++ci) {
        int c = cg2 * 64 + ci;
        dst[(size_t)c * NPOS] = (Fs[c * F_STRIDE + p] - mu) * rs * lnw_s[c] + lnb_s[c];
    }
}

// ---------------------------------------------------------------------------
extern "C" void kernel_launch(void* const* d_in, const int* in_sizes, int n_in,
                              void* d_out, int out_size, void* d_ws, size_t ws_size,
                              hipStream_t stream)
{
    const float* x1  = (const float*)d_in[0];
    const float* x2  = (const float*)d_in[1];
    const float* qw  = (const float*)d_in[2];
    const float* qb  = (const float*)d_in[3];
    const float* kw  = (const float*)d_in[4];
    const float* kb  = (const float*)d_in[5];
    const float* vw  = (const float*)d_in[6];
    const float* vb  = (const float*)d_in[7];
    const float* lnw = (const float*)d_in[8];
    const float* lnb = (const float*)d_in[9];

    const size_t tsz = (size_t)BATCH * NPOS * CDIM;
    f16* Qg  = (f16*)d_ws;
    f16* Kg  = Qg + tsz;
    f16* Vg  = Kg + tsz;
    f16* W16 = Vg + tsz;                          // 384 KB f16 weights
    float* Fp = (float*)(W16 + 3 * CDIM * CDIM);  // 32 MB fp32; total ws ~57 MB

    wconv_kernel<<<12, 256, 0, stream>>>(qw, kw, vw, W16);
    gemm_kernel<<<768, 256, 0, stream>>>(x1, x2, W16, qb, kb, vb, Qg, Kg, Vg);
    attn_kernel<<<512, 256, 0, stream>>>(Qg, Kg, Vg, Fp);
    merge_ln_kernel<<<256, 256, 0, stream>>>(Fp, lnw, lnb, (float*)d_out);
}